// Round 14
// baseline (225.031 us; speedup 1.0000x reference)
//
#include <hip/hip_runtime.h>

typedef unsigned short u16;
typedef __bf16 bf16x8 __attribute__((ext_vector_type(8)));
typedef float f32x4 __attribute__((ext_vector_type(4)));
typedef u16   u16x8 __attribute__((ext_vector_type(8)));

__device__ __forceinline__ u16 f2bf(float f) {
  __bf16 b = (__bf16)f;
  return __builtin_bit_cast(u16, b);
}
__device__ __forceinline__ float bf2f(u16 u) {
  unsigned int x = ((unsigned int)u) << 16;
  return __builtin_bit_cast(float, x);
}

// async global->LDS, 16B per lane. LDS dest: wave-uniform base + lane*16.
__device__ __forceinline__ void gll16(const u16* g, u16* l) {
  __builtin_amdgcn_global_load_lds(
      (const __attribute__((address_space(1))) void*)g,
      (__attribute__((address_space(3))) void*)l, 16, 0, 0);
}

// ---------------- f32 -> bf16 conversion kernels ----------------------------
__global__ __launch_bounds__(256) void convw_kernel(
    const float* __restrict__ w0, const float* __restrict__ w1,
    const float* __restrict__ w2, const float* __restrict__ w3,
    u16* __restrict__ o0, u16* __restrict__ o1,
    u16* __restrict__ o2, u16* __restrict__ o3)
{
  const int z = blockIdx.z;
  const float* s = (z == 0) ? w0 : (z == 1) ? w1 : (z == 2) ? w2 : w3;
  u16* o = (z == 0) ? o0 : (z == 1) ? o1 : (z == 2) ? o2 : o3;
  const long i = ((long)blockIdx.x * 256 + threadIdx.x) * 8;
  f32x4 a = *(const f32x4*)(s + i);
  f32x4 b = *(const f32x4*)(s + i + 4);
  u16x8 r;
#pragma unroll
  for (int e = 0; e < 4; ++e) { r[e] = f2bf(a[e]); r[e + 4] = f2bf(b[e]); }
  *(u16x8*)(o + i) = r;
}

__global__ __launch_bounds__(256) void convact_kernel(
    const float* __restrict__ a0, const float* __restrict__ a1,
    const float* __restrict__ a2,
    u16* __restrict__ o0, u16* __restrict__ o1, u16* __restrict__ o2)
{
  const int z = blockIdx.z;
  const float* s = (z == 0) ? a0 : (z == 1) ? a1 : a2;
  u16* o = (z == 0) ? o0 : (z == 1) ? o1 : o2;
  const long i = ((long)blockIdx.x * 256 + threadIdx.x) * 8;
  f32x4 a = *(const f32x4*)(s + i);
  f32x4 b = *(const f32x4*)(s + i + 4);
  u16x8 r;
#pragma unroll
  for (int e = 0; e < 4; ++e) { r[e] = f2bf(a[e]); r[e + 4] = f2bf(b[e]); }
  *(u16x8*)(o + i) = r;
}

// ---------------- MFMA GEMM: 2-deep pipeline, counted vmcnt (T3/T4) ---------
// C[m,n] = sum_k A[m,k]*W[n,k] + bias[n]. A: [rows][1024] bf16.
// Bw: [1024][1024] bf16 (row n = output col n). 64x128 tile, BK=64, 16 K-steps.
// Double-buffered LDS; stage(t+2) issued after compute(t); s_waitcnt vmcnt(6)
// waits only tile t's 6 global_load_lds (t+1 stays in flight). Swizzle as r13:
// linear LDS dest + pre-swizzled source col; read offset (kk+8lg)^((r&7)<<3).
template<int OUT_F32>
__global__ __launch_bounds__(256, 3) void gemm_p2(
    const u16* __restrict__ A0, const u16* __restrict__ A1, const u16* __restrict__ A2,
    const u16* __restrict__ B0, const u16* __restrict__ B1, const u16* __restrict__ B2,
    const float* __restrict__ g0, const float* __restrict__ g1, const float* __restrict__ g2,
    void* __restrict__ C0, void* __restrict__ C1, void* __restrict__ C2, int Mvalid)
{
  const int z = blockIdx.z;
  const u16* Ab = (z == 0) ? A0 : (z == 1) ? A1 : A2;
  const u16* Bw = (z == 0) ? B0 : (z == 1) ? B1 : B2;
  const float* bias = (z == 0) ? g0 : (z == 1) ? g1 : g2;
  void* Cout = (z == 0) ? C0 : (z == 1) ? C1 : C2;

  __shared__ __align__(16) u16 As[2][64 * 64];
  __shared__ __align__(16) u16 Bs[2][128 * 64];

  const int tid = threadIdx.x;
  const int wid = tid >> 6, lane = tid & 63, ln = lane & 15, lg = lane >> 4;
  const int row0 = blockIdx.x * 64, col0 = blockIdx.y * 128;
  const int wr = (wid >> 1) * 32, wc = (wid & 1) * 64;
  const int lr8 = lane >> 3;                       // row within 8-row group
  const int kslot = 8 * ((lane & 7) ^ lr8);        // pre-swizzled source k-offset

  auto stage = [&](int buf, int kt) {
    const int k0 = kt * 64;
#pragma unroll
    for (int c = 0; c < 2; ++c) {                  // A: 2 wave-loads (8 rows each)
      int base = wid * 16 + c * 8;
      long gr = row0 + base + lr8; if (gr >= Mvalid) gr = Mvalid - 1;
      gll16(Ab + gr * 1024 + k0 + kslot, &As[buf][base * 64]);
    }
#pragma unroll
    for (int c = 0; c < 4; ++c) {                  // B: 4 wave-loads
      int base = wid * 32 + c * 8;
      gll16(Bw + (long)(col0 + base + lr8) * 1024 + k0 + kslot, &Bs[buf][base * 64]);
    }
  };

  f32x4 acc[2][4] = {};
  stage(0, 0);
  stage(1, 1);                                     // 12 loads in flight

  for (int kt = 0; kt < 16; ++kt) {
    const int buf = kt & 1;
    if (kt < 15) asm volatile("s_waitcnt vmcnt(6)" ::: "memory");
    else         asm volatile("s_waitcnt vmcnt(0)" ::: "memory");
    __builtin_amdgcn_sched_barrier(0);
    __builtin_amdgcn_s_barrier();                  // tile kt staged for all waves

#pragma unroll
    for (int kk = 0; kk < 64; kk += 32) {
      bf16x8 af[2], bfr[4];
#pragma unroll
      for (int i = 0; i < 2; ++i) {
        int r = wr + i * 16 + ln;
        af[i] = *(const bf16x8*)&As[buf][r * 64 + ((kk + 8 * lg) ^ ((r & 7) << 3))];
      }
#pragma unroll
      for (int j = 0; j < 4; ++j) {
        int r = wc + j * 16 + ln;
        bfr[j] = *(const bf16x8*)&Bs[buf][r * 64 + ((kk + 8 * lg) ^ ((r & 7) << 3))];
      }
#pragma unroll
      for (int i = 0; i < 2; ++i)
#pragma unroll
        for (int j = 0; j < 4; ++j)
          acc[i][j] = __builtin_amdgcn_mfma_f32_16x16x32_bf16(af[i], bfr[j], acc[i][j], 0, 0, 0);
    }

    __builtin_amdgcn_s_barrier();                  // all waves done reading buf
    if (kt + 2 < 16) stage(buf, kt + 2);           // refill freed buffer
  }

  float bj[4];
#pragma unroll
  for (int j = 0; j < 4; ++j) bj[j] = bias[col0 + wc + j * 16 + ln];
#pragma unroll
  for (int i = 0; i < 2; ++i)
#pragma unroll
    for (int j = 0; j < 4; ++j)
#pragma unroll
      for (int reg = 0; reg < 4; ++reg) {
        int r = row0 + wr + i * 16 + 4 * lg + reg;
        int c = col0 + wc + j * 16 + ln;
        if (r < Mvalid) {
          float v = acc[i][j][reg] + bj[j];
          if constexpr (OUT_F32) ((float*)Cout)[(long)r * 1024 + c] = v;
          else                   ((u16*)Cout)[(long)r * 1024 + c] = f2bf(v);
        }
      }
}

// ---------------- MFMA flash attention (unchanged, green since round 9) -----
__global__ __launch_bounds__(256) void MaskedMultiheadAttention_51591147160164_kernel(
    const u16* __restrict__ Qb, const u16* __restrict__ Kb,
    const u16* __restrict__ Vb, const int* __restrict__ maskp,
    float* __restrict__ Aout, u16* __restrict__ ctx)
{
  __shared__ __align__(16) u16 Qs[64 * 72];
  __shared__ __align__(16) u16 Ks[32 * 72];
  __shared__ __align__(16) u16 Vs[64 * 40];
  __shared__ __align__(16) u16 Ps[4][16 * 40];

  const int qb = 15 - blockIdx.x;
  const int bh = blockIdx.y;
  const int b = bh >> 4, h = bh & 15;
  const int q0 = qb * 64;
  const int tid = threadIdx.x;
  const int wid = tid >> 6, lane = tid & 63, ln = lane & 15, lg = lane >> 4;
  const int nkt = 2 * qb + 2;

#pragma unroll
  for (int p = 0; p < 2; ++p) {
    int idx = p * 256 + tid;
    int r = idx >> 3, u = idx & 7;
    int tok = q0 + r; if (tok > 999) tok = 999;
    *(u16x8*)&Qs[r * 72 + u * 8] =
        *(const u16x8*)(Qb + (long)(b * 1000 + tok) * 1024 + h * 64 + u * 8);
  }
  __syncthreads();

  bf16x8 qf0, qf1;
  {
    int r = wid * 16 + ln;
    qf0 = *(const bf16x8*)&Qs[r * 72 +      8 * lg];
    qf1 = *(const bf16x8*)&Qs[r * 72 + 32 + 8 * lg];
  }

  const int kr = tid >> 3, ku = tid & 7;
  const int qrow = q0 + wid * 16 + 4 * lg;

  auto computeS = [&](f32x4 sf[2]) {
#pragma unroll
    for (int j = 0; j < 2; ++j) {
      int kk = j * 16 + ln;
      bf16x8 kf0 = *(const bf16x8*)&Ks[kk * 72 +      8 * lg];
      bf16x8 kf1 = *(const bf16x8*)&Ks[kk * 72 + 32 + 8 * lg];
      f32x4 zz = {0.f, 0.f, 0.f, 0.f};
      zz = __builtin_amdgcn_mfma_f32_16x16x32_bf16(qf0, kf0, zz, 0, 0, 0);
      zz = __builtin_amdgcn_mfma_f32_16x16x32_bf16(qf1, kf1, zz, 0, 0, 0);
      sf[j] = zz;
    }
  };

  float m[4], l[4];
#pragma unroll
  for (int i = 0; i < 4; ++i) { m[i] = -3.0e38f; l[i] = 0.f; }

  for (int kt = 0; kt < nkt; ++kt) {
    int tok = kt * 32 + kr; if (tok > 999) tok = 999;
    u16x8 w = *(const u16x8*)(Kb + (long)(b * 1000 + tok) * 1024 + h * 64 + ku * 8);
    __syncthreads();
    *(u16x8*)&Ks[kr * 72 + ku * 8] = w;
    __syncthreads();

    f32x4 sf[2]; computeS(sf);
    int ki0 = kt * 32 + ln, ki1 = ki0 + 16;
    int mv0 = (ki0 < 1000) ? maskp[b * 1000 + ki0] : 0;
    int mv1 = (ki1 < 1000) ? maskp[b * 1000 + ki1] : 0;
#pragma unroll
    for (int reg = 0; reg < 4; ++reg) {
      int qi = qrow + reg;
      float s0 = (mv0 && ki0 <= qi) ? sf[0][reg] * 0.125f : -1.0e30f;
      float s1 = (mv1 && ki1 <= qi) ? sf[1][reg] * 0.125f : -1.0e30f;
      float mx = fmaxf(s0, s1);
#pragma unroll
      for (int d = 1; d < 16; d <<= 1) mx = fmaxf(mx, __shfl_xor(mx, d));
      float mnew = fmaxf(m[reg], mx);
      float sum = __expf(s0 - mnew) + __expf(s1 - mnew);
#pragma unroll
      for (int d = 1; d < 16; d <<= 1) sum += __shfl_xor(sum, d);
      l[reg] = l[reg] * __expf(m[reg] - mnew) + sum;
      m[reg] = mnew;
    }
  }

  float rl[4];
#pragma unroll
  for (int i = 0; i < 4; ++i) rl[i] = 1.0f / l[i];

  f32x4 cacc[4] = {};

  for (int kt = 0; kt < nkt; ++kt) {
    int tok = kt * 32 + kr; if (tok > 999) tok = 999;
    u16x8 w = *(const u16x8*)(Kb + (long)(b * 1000 + tok) * 1024 + h * 64 + ku * 8);
    u16x8 v8 = *(const u16x8*)(Vb + (long)(b * 1000 + tok) * 1024 + h * 64 + ku * 8);
    __syncthreads();
    *(u16x8*)&Ks[kr * 72 + ku * 8] = w;
#pragma unroll
    for (int e = 0; e < 8; ++e)
      Vs[(ku * 8 + e) * 40 + kr] = v8[e];
    __syncthreads();

    f32x4 sf[2]; computeS(sf);
#pragma unroll
    for (int j = 0; j < 2; ++j) {
      int ki = kt * 32 + j * 16 + ln;
      int mv = (ki < 1000) ? maskp[b * 1000 + ki] : 0;
#pragma unroll
      for (int reg = 0; reg < 4; ++reg) {
        int qi = qrow + reg;
        float p = (mv && ki <= qi) ? __expf(sf[j][reg] * 0.125f - m[reg]) * rl[reg] : 0.f;
        if (qi < 1000 && ki < 1000)
          Aout[((long)bh * 1000 + qi) * 1000 + ki] = p;
        Ps[wid][(4 * lg + reg) * 40 + j * 16 + ln] = f2bf(p);
      }
    }
    __syncthreads();
    bf16x8 pf = *(const bf16x8*)&Ps[wid][ln * 40 + 8 * lg];
#pragma unroll
    for (int jn = 0; jn < 4; ++jn) {
      bf16x8 vf = *(const bf16x8*)&Vs[(jn * 16 + ln) * 40 + 8 * lg];
      cacc[jn] = __builtin_amdgcn_mfma_f32_16x16x32_bf16(pf, vf, cacc[jn], 0, 0, 0);
    }
  }

#pragma unroll
  for (int jn = 0; jn < 4; ++jn)
#pragma unroll
    for (int reg = 0; reg < 4; ++reg) {
      int qi = qrow + reg;
      if (qi < 1000)
        ctx[(long)(b * 1000 + qi) * 1024 + h * 64 + jn * 16 + ln] = f2bf(cacc[jn][reg]);
    }
}

// ---------------- launch ----------------------------------------------------
extern "C" void kernel_launch(void* const* d_in, const int* in_sizes, int n_in,
                              void* d_out, int out_size, void* d_ws, size_t ws_size,
                              hipStream_t stream)
{
  const float* q  = (const float*)d_in[0];
  const float* k  = (const float*)d_in[1];
  const float* v  = (const float*)d_in[2];
  const int*  msk = (const int*)d_in[3];
  const float* Wq = (const float*)d_in[4];
  const float* bq = (const float*)d_in[5];
  const float* Wk = (const float*)d_in[6];
  const float* bk = (const float*)d_in[7];
  const float* Wv = (const float*)d_in[8];
  const float* bv = (const float*)d_in[9];
  const float* Wp = (const float*)d_in[10];
  const float* bp = (const float*)d_in[11];

  u16* ws  = (u16*)d_ws;                     // 56 MB total
  u16* Qc  = ws;                             // [4000][1024] bf16 (q cast; ctx aliases later)
  u16* Kc  = ws + 4096000u;                  // [4000][1024] bf16 (k cast)
  u16* Vc  = ws + 2u * 4096000u;             // [4000][1024] bf16 (v cast)
  u16* Qb  = ws + 3u * 4096000u;             // [4000][1024] bf16 (Q proj)
  u16* Kb  = ws + 4u * 4096000u;             // [4000][1024] bf16 (K proj)
  u16* Vb  = ws + 5u * 4096000u;             // [4000][1024] bf16 (V proj)
  u16* wqb = ws + 6u * 4096000u;             // [1024][1024] bf16
  u16* wkb = wqb + (1u << 20);
  u16* wvb = wkb + (1u << 20);
  u16* wpb = wvb + (1u << 20);
  u16* ctx = Qc;                             // alias: Qc dead after QKV GEMM

  float* Xout = (float*)d_out;               // [4000][1024] f32 (output x)
  float* Aout = Xout + 4096000;              // [64][1000][1000] f32 (output A)

  convw_kernel<<<dim3(512, 1, 4), 256, 0, stream>>>(Wq, Wk, Wv, Wp, wqb, wkb, wvb, wpb);
  convact_kernel<<<dim3(2000, 1, 3), 256, 0, stream>>>(q, k, v, Qc, Kc, Vc);
  // fused QKV projections: 64x128 tiles, grid (63,8,3)=1512 blocks (3/CU, 2 rounds)
  gemm_p2<0><<<dim3(63, 8, 3), 256, 0, stream>>>(
      Qc, Kc, Vc, wqb, wkb, wvb, bq, bk, bv, Qb, Kb, Vb, 4000);
  MaskedMultiheadAttention_51591147160164_kernel<<<dim3(16, 64), 256, 0, stream>>>(
      Qb, Kb, Vb, msk, Aout, ctx);
  // output projection: 64x128 tiles, grid (63,8)=504 blocks (2/CU)
  gemm_p2<1><<<dim3(63, 8, 1), 256, 0, stream>>>(
      ctx, ctx, ctx, wpb, wpb, wpb, bp, bp, bp, Xout, Xout, Xout, 4000);
}